// Round 9
// baseline (210.696 us; speedup 1.0000x reference)
//
#include <hip/hip_runtime.h>
#include <hip/hip_bf16.h>

// ---------------------------------------------------------------------------
// Fused GAT (PyG GATConv, concat=False/head-mean) + 2-layer MLP head.
// 4 launches:
//   prep_small:  zero cnt + watt[8][256] + Wstk bf16 + w1t bf16
//   cast_fill:   [block-split] cast x->bf16 + EXACT f32 scores  ||
//                direct-slot bucket fill (CAP=64 slots/node, slot-assign only)
//   aggregate_x: phase0: lane l = slot l computes w4 + den via shfl butterfly;
//                main loop: readlane-broadcast (w4, src) from lane i,
//                G[n,h*256+k] = 0.25/den_h * sum_e w4[h]*x_bf16[src,k]
//   tail_kernel: relu(G@Wstk+bias) -> relu(@w1t+b1) -> @w2+b2 -> out
// CAP=64 == wavefront size: slot<->lane bijection. Max in-degree of
// Binomial(800k,1/50k)+self-loop ~40; P(any node > 64) ~ 1e-19.
// edge_index arrives as int32 [2,E].
// ---------------------------------------------------------------------------

#define LEAKY(x) ((x) > 0.0f ? (x) : 0.2f * (x))
#define CAP 64

typedef __attribute__((ext_vector_type(8))) short short8v;
typedef __attribute__((ext_vector_type(4))) float floatx4;

__device__ __forceinline__ unsigned f2b(float f) {  // f32 -> bf16 bits (RNE)
    unsigned u = __float_as_uint(f);
    return (u + 0x7fffu + ((u >> 16) & 1u)) >> 16;
}

__device__ __forceinline__ float rlf(float v, int i) {  // readlane (uniform i)
    return __uint_as_float(
        __builtin_amdgcn_readlane(__float_as_uint(v), (unsigned)i));
}

__device__ __forceinline__ void load_lds16(const void* g, void* lds) {
    __builtin_amdgcn_global_load_lds(
        (const __attribute__((address_space(1))) void*)g,
        (__attribute__((address_space(3))) void*)lds, 16, 0, 0);
}

// ---------------- prep: zero cnt | watt | Wstk bf16 | w1t bf16 --------------
// blocks [0,196): zero cnt; [196,204): watt; [204,716): WT2; [716,780): w1t
__global__ __launch_bounds__(256) void prep_small(
    const float* __restrict__ W, const float* __restrict__ att_src,
    const float* __restrict__ att_dst, const float* __restrict__ w1,
    int* __restrict__ cnt, float* __restrict__ watt,
    ushort* __restrict__ WT2, ushort* __restrict__ w1t, int N) {
    int pb = blockIdx.x;
    int t = threadIdx.x;
    if (pb < 196) {
        int i = pb * 256 + t;
        if (i < N) cnt[i] = 0;
    } else if (pb < 204) {
        int idx = (pb - 196) * 256 + t;  // 0..2047
        int k = idx >> 3;
        int h8 = idx & 7;
        int h = h8 & 3;
        const float* att = (h8 < 4) ? att_src : att_dst;
        const float* wrow = W + (size_t)k * 512 + h * 128;
        const float* arow = att + h * 128;
        float s = 0.f;
#pragma unroll 4
        for (int c = 0; c < 128; ++c) s += wrow[c] * arow[c];
        watt[h8 * 256 + k] = s;
    } else if (pb < 716) {
        int idx = (pb - 204) * 256 + t;  // 0..131071
        int c = idx >> 10;
        int kk = idx & 1023;
        int h = kk >> 8, k = kk & 255;
        WT2[c * 1024 + kk] = (ushort)f2b(W[(size_t)k * 512 + h * 128 + c]);
    } else {
        int idx = (pb - 716) * 256 + t;  // 0..16383
        int c = idx >> 7, k = idx & 127;
        w1t[c * 128 + k] = (ushort)f2b(w1[(size_t)k * 128 + c]);
    }
}

// ---------------- cast+score || slot-assign fill (block-range split) --------
__global__ __launch_bounds__(256) void cast_fill(
    const float* __restrict__ x, const float* __restrict__ watt,  // [8][256]
    ushort* __restrict__ xb, float* __restrict__ asrc,
    float* __restrict__ adst, const int* __restrict__ ei,
    int* __restrict__ cnt, int* __restrict__ esrc, int N, int E, int CB) {
    if ((int)blockIdx.x < CB) {
        // ---- cast x -> bf16 + EXACT f32 attention scores ----
        int w = threadIdx.x >> 6, l = threadIdx.x & 63;
        int n = blockIdx.x * 4 + w;
        if (n >= N) return;
        float4 xv = *(const float4*)(x + (size_t)n * 256 + l * 4);
        ushort4 ub;
        ub.x = (ushort)f2b(xv.x);
        ub.y = (ushort)f2b(xv.y);
        ub.z = (ushort)f2b(xv.z);
        ub.w = (ushort)f2b(xv.w);
        *(ushort4*)(xb + (size_t)n * 256 + l * 4) = ub;

        float acc[8];
#pragma unroll
        for (int h8 = 0; h8 < 8; ++h8) {
            float4 wv = *(const float4*)(watt + h8 * 256 + l * 4);
            acc[h8] = xv.x * wv.x + xv.y * wv.y + xv.z * wv.z + xv.w * wv.w;
        }
#pragma unroll
        for (int o = 32; o; o >>= 1)
#pragma unroll
            for (int h8 = 0; h8 < 8; ++h8) acc[h8] += __shfl_xor(acc[h8], o);
        if (l == 0) {
#pragma unroll
            for (int h = 0; h < 4; ++h) {
                asrc[n * 4 + h] = acc[h];
                adst[n * 4 + h] = acc[4 + h];
            }
        }
    } else {
        // ---- direct-slot bucket fill (slot assignment only) ----
        int e = ((int)blockIdx.x - CB) * 256 + (int)threadIdx.x;
        if (e >= E + N) return;
        int s, d;
        if (e < E) {
            s = ei[e];
            d = ei[E + e];
        } else {
            s = d = e - E;
        }
        if (d < 0 || d >= N || s < 0 || s >= N) return;
        int slot = atomicAdd(&cnt[d], 1);
        if (slot < CAP) esrc[d * CAP + slot] = s;
    }
}

// ---------------- aggregation in INPUT space --------------------------------
// one wave per node. Phase 0: lane l = slot l computes w4 (exp once per edge)
// + den via shfl butterfly. Main loop: edge i's w4/src broadcast via readlane
// (uniform index -> SGPR operand), gather 8B/lane of x_bf16[src].
#define EDGE_FMA_S(wx, wy, wz, ww, g)                                        \
    {                                                                        \
        float _e0 = __uint_as_float((g).x << 16);                            \
        float _e1 = __uint_as_float((g).x & 0xffff0000u);                    \
        float _e2 = __uint_as_float((g).y << 16);                            \
        float _e3 = __uint_as_float((g).y & 0xffff0000u);                    \
        acc[0][0] += (wx) * _e0; acc[0][1] += (wx) * _e1;                    \
        acc[0][2] += (wx) * _e2; acc[0][3] += (wx) * _e3;                    \
        acc[1][0] += (wy) * _e0; acc[1][1] += (wy) * _e1;                    \
        acc[1][2] += (wy) * _e2; acc[1][3] += (wy) * _e3;                    \
        acc[2][0] += (wz) * _e0; acc[2][1] += (wz) * _e1;                    \
        acc[2][2] += (wz) * _e2; acc[2][3] += (wz) * _e3;                    \
        acc[3][0] += (ww) * _e0; acc[3][1] += (ww) * _e1;                    \
        acc[3][2] += (ww) * _e2; acc[3][3] += (ww) * _e3;                    \
    }

__global__ __launch_bounds__(256) void aggregate_x(
    const ushort* __restrict__ xb, const int* __restrict__ cnt,
    const int* __restrict__ esrc, const float* __restrict__ asrc,
    const float* __restrict__ adst, ushort* __restrict__ G, int N) {
    const int t = threadIdx.x;
    const int wv = t >> 6, l = t & 63;
    const int n = blockIdx.x * 4 + wv;
    if (n >= N) return;
    const int beg = n * CAP;
    const int deg = min(cnt[n], CAP);
    const uint loff = (uint)l * 4u;

    // ---- phase 0: per-slot weights (lane l = slot l) + denominator ----
    float4 ad = ((const float4*)adst)[n];
    int s_l = 0;
    float4 wl = {0.f, 0.f, 0.f, 0.f};
    if (l < deg) {
        s_l = esrc[beg + l];
        float4 as = ((const float4*)asrc)[s_l];
        wl.x = __expf(LEAKY(as.x + ad.x));
        wl.y = __expf(LEAKY(as.y + ad.y));
        wl.z = __expf(LEAKY(as.z + ad.z));
        wl.w = __expf(LEAKY(as.w + ad.w));
    }
    float dx = wl.x, dy = wl.y, dz = wl.z, dw = wl.w;
#pragma unroll
    for (int o = 32; o; o >>= 1) {
        dx += __shfl_xor(dx, o);
        dy += __shfl_xor(dy, o);
        dz += __shfl_xor(dz, o);
        dw += __shfl_xor(dw, o);
    }
    const float sc0 = 0.25f / dx, sc1 = 0.25f / dy;
    const float sc2 = 0.25f / dz, sc3 = 0.25f / dw;

    float acc[4][4];
#pragma unroll
    for (int h = 0; h < 4; ++h)
#pragma unroll
        for (int j = 0; j < 4; ++j) acc[h][j] = 0.f;

    // ---- main loop: readlane broadcast of (src, w4), coalesced 8B gather ---
    int i = 0;
    const int deg4 = deg & ~3;
    for (; i < deg4; i += 4) {
        int s0 = __builtin_amdgcn_readlane(s_l, i + 0);
        int s1 = __builtin_amdgcn_readlane(s_l, i + 1);
        int s2 = __builtin_amdgcn_readlane(s_l, i + 2);
        int s3 = __builtin_amdgcn_readlane(s_l, i + 3);
        uint2 g0 = *(const uint2*)(xb + ((uint)s0 * 256u + loff));
        uint2 g1 = *(const uint2*)(xb + ((uint)s1 * 256u + loff));
        uint2 g2 = *(const uint2*)(xb + ((uint)s2 * 256u + loff));
        uint2 g3 = *(const uint2*)(xb + ((uint)s3 * 256u + loff));
        float w00 = rlf(wl.x, i + 0), w01 = rlf(wl.y, i + 0);
        float w02 = rlf(wl.z, i + 0), w03 = rlf(wl.w, i + 0);
        float w10 = rlf(wl.x, i + 1), w11 = rlf(wl.y, i + 1);
        float w12 = rlf(wl.z, i + 1), w13 = rlf(wl.w, i + 1);
        float w20 = rlf(wl.x, i + 2), w21 = rlf(wl.y, i + 2);
        float w22 = rlf(wl.z, i + 2), w23 = rlf(wl.w, i + 2);
        float w30 = rlf(wl.x, i + 3), w31 = rlf(wl.y, i + 3);
        float w32 = rlf(wl.z, i + 3), w33 = rlf(wl.w, i + 3);
        EDGE_FMA_S(w00, w01, w02, w03, g0);
        EDGE_FMA_S(w10, w11, w12, w13, g1);
        EDGE_FMA_S(w20, w21, w22, w23, g2);
        EDGE_FMA_S(w30, w31, w32, w33, g3);
    }
    for (; i < deg; ++i) {
        int s0 = __builtin_amdgcn_readlane(s_l, i);
        uint2 g0 = *(const uint2*)(xb + ((uint)s0 * 256u + loff));
        float w00 = rlf(wl.x, i), w01 = rlf(wl.y, i);
        float w02 = rlf(wl.z, i), w03 = rlf(wl.w, i);
        EDGE_FMA_S(w00, w01, w02, w03, g0);
    }

    const float sc[4] = {sc0, sc1, sc2, sc3};
#pragma unroll
    for (int h = 0; h < 4; ++h) {
        ushort4 o;
        o.x = (ushort)f2b(acc[h][0] * sc[h]);
        o.y = (ushort)f2b(acc[h][1] * sc[h]);
        o.z = (ushort)f2b(acc[h][2] * sc[h]);
        o.w = (ushort)f2b(acc[h][3] * sc[h]);
        *(ushort4*)(G + (size_t)n * 1024 + h * 256 + l * 4) = o;
    }
}

// ---------------- fused tail: G@Wstk -> relu -> @w1t -> relu -> @w2 ---------
__global__ __launch_bounds__(256) void tail_kernel(
    const ushort* __restrict__ Gb,      // [N,1024] bf16
    const ushort* __restrict__ Wstk,    // [128,1024] bf16 (row = out col)
    const ushort* __restrict__ w1t,     // [128,128] bf16 (row = out col)
    const float* __restrict__ gat_bias, const float* __restrict__ b1,
    const float* __restrict__ w2, const float* __restrict__ b2,
    float* __restrict__ out, int N) {
    __shared__ char smem[65 * 1024];
    char* AlsB = smem;                 // 16K stage-1 A tile
    char* BlsB = smem + 16 * 1024;     // 16K stage-1 B tile
    char* ndh = smem;                  // 32K nodeh bf16 (aliases A+B)
    char* w1ls = smem + 32 * 1024;     // 32K w1t bf16
    float* sums = (float*)(smem + 64 * 1024);  // [2][128] f32

    const int t = threadIdx.x;
    const int w = t >> 6;
    const int l = t & 63;
    const int wr = w >> 1, wc = w & 1;
    const int row0 = blockIdx.x * 128;

    float gbr[4], b1r[4], w2r[4];
#pragma unroll
    for (int n = 0; n < 4; ++n) {
        int cg = wc * 64 + n * 16 + (l & 15);
        gbr[n] = gat_bias[cg];
        b1r[n] = b1[cg];
        w2r[n] = w2[cg];
    }

    floatx4 acc[4][4];
#pragma unroll
    for (int m = 0; m < 4; ++m)
#pragma unroll
        for (int n = 0; n < 4; ++n) acc[m][n] = {0.f, 0.f, 0.f, 0.f};

    const int lr = l >> 3;
    const int kbyt = ((l & 7) ^ lr) << 4;
    const char* Abase = (const char*)Gb;
    const char* Bbase = (const char*)Wstk;

    // ---- stage 1: G @ Wstk, K=1024 ----
    for (int ks = 0; ks < 16; ++ks) {
        const int k0b = ks * 128;
#pragma unroll
        for (int c = 0; c < 4; ++c) {
            int rowt = w * 32 + c * 8 + lr;
            int rA = row0 + rowt;
            if (rA >= N) rA = N - 1;
            load_lds16(Abase + (size_t)rA * 2048 + k0b + kbyt,
                       AlsB + (w * 4 + c) * 1024);
            load_lds16(Bbase + (size_t)rowt * 2048 + k0b + kbyt,
                       BlsB + (w * 4 + c) * 1024);
        }
        __syncthreads();

#pragma unroll
        for (int kk = 0; kk < 2; ++kk) {
            const int kb_g = kk * 64 + (l >> 4) * 16;
            const int swz = (l & 7) << 4;
            short8v a[4], b[4];
#pragma unroll
            for (int m = 0; m < 4; ++m) {
                int row = wr * 64 + m * 16 + (l & 15);
                a[m] = *(const short8v*)(AlsB + row * 128 + (kb_g ^ swz));
            }
#pragma unroll
            for (int n = 0; n < 4; ++n) {
                int row = wc * 64 + n * 16 + (l & 15);
                b[n] = *(const short8v*)(BlsB + row * 128 + (kb_g ^ swz));
            }
#pragma unroll
            for (int m = 0; m < 4; ++m)
#pragma unroll
                for (int n = 0; n < 4; ++n)
                    acc[m][n] = __builtin_amdgcn_mfma_f32_16x16x32_bf16(
                        a[m], b[n], acc[m][n], 0, 0, 0);
        }
        __syncthreads();
    }

    // ---- epilogue 1: stage w1t (async) + write nodeh bf16 to LDS ----
#pragma unroll
    for (int p = 0; p < 8; ++p) {
        int row = p * 16 + w * 4 + (l >> 4);
        int bcol = (l & 15) * 16;
        load_lds16((const char*)w1t + row * 256 + (bcol ^ ((row & 7) << 4)),
                   w1ls + p * 4096 + w * 1024);
    }
#pragma unroll
    for (int m = 0; m < 4; ++m) {
#pragma unroll
        for (int reg = 0; reg < 4; ++reg) {
            int r = wr * 64 + m * 16 + ((l >> 4) << 2) + reg;
            int srow = (r & 7) << 4;
#pragma unroll
            for (int n = 0; n < 4; ++n) {
                int c = wc * 64 + n * 16 + (l & 15);
                float v = acc[m][n][reg] + gbr[n];
                v = v > 0.f ? v : 0.f;
                *(ushort*)(ndh + r * 256 + ((2 * c) ^ srow)) = (ushort)f2b(v);
            }
        }
    }
    __syncthreads();  // drains vmcnt (w1ls) + lgkm (ndh writes)

    // ---- stage 2: y1 = relu(nodeh @ w1t + b1), K=128 ----
    floatx4 acc2[4][4];
#pragma unroll
    for (int m = 0; m < 4; ++m)
#pragma unroll
        for (int n = 0; n < 4; ++n) acc2[m][n] = {0.f, 0.f, 0.f, 0.f};

#pragma unroll
    for (int kk = 0; kk < 4; ++kk) {
        const int kb = kk * 64 + (l >> 4) * 16;
        short8v a2[4], b2f[4];
#pragma unroll
        for (int m = 0; m < 4; ++m) {
            int r = wr * 64 + m * 16 + (l & 15);
            a2[m] = *(const short8v*)(ndh + r * 256 + (kb ^ ((r & 7) << 4)));
        }
#pragma unroll
        for (int n = 0; n < 4; ++n) {
            int r = wc * 64 + n * 16 + (l & 15);
            b2f[n] = *(const short8v*)(w1ls + r * 256 + (kb ^ ((r & 7) << 4)));
        }
#pragma unroll
        for (int m = 0; m < 4; ++m)
#pragma unroll
            for (int n = 0; n < 4; ++n)
                acc2[m][n] = __builtin_amdgcn_mfma_f32_16x16x32_bf16(
                    a2[m], b2f[n], acc2[m][n], 0, 0, 0);
    }

    // ---- stage 3: out = y1 @ w2 + b2 (in-register) ----
    float part[4][4];
#pragma unroll
    for (int m = 0; m < 4; ++m)
#pragma unroll
        for (int reg = 0; reg < 4; ++reg) {
            float s = 0.f;
#pragma unroll
            for (int n = 0; n < 4; ++n) {
                float y = acc2[m][n][reg] + b1r[n];
                y = y > 0.f ? y : 0.f;
                s += y * w2r[n];
            }
            part[m][reg] = s;
        }
#pragma unroll
    for (int o = 1; o < 16; o <<= 1)
#pragma unroll
        for (int m = 0; m < 4; ++m)
#pragma unroll
            for (int reg = 0; reg < 4; ++reg)
                part[m][reg] += __shfl_xor(part[m][reg], o);
    if ((l & 15) == 0) {
#pragma unroll
        for (int m = 0; m < 4; ++m)
#pragma unroll
            for (int reg = 0; reg < 4; ++reg) {
                int r = wr * 64 + m * 16 + ((l >> 4) << 2) + reg;
                sums[wc * 128 + r] = part[m][reg];
            }
    }
    __syncthreads();
    if (t < 128) {
        int rg = row0 + t;
        if (rg < N) out[rg] = sums[t] + sums[128 + t] + b2[0];
    }
}

// ---------------------------------------------------------------------------
extern "C" void kernel_launch(void* const* d_in, const int* in_sizes, int n_in,
                              void* d_out, int out_size, void* d_ws,
                              size_t ws_size, hipStream_t stream) {
    const float* x = (const float*)d_in[0];
    const int* ei = (const int*)d_in[1];  // int32 [2,E]
    const float* W = (const float*)d_in[2];
    const float* att_src = (const float*)d_in[3];
    const float* att_dst = (const float*)d_in[4];
    const float* gat_bias = (const float*)d_in[5];
    const float* w1 = (const float*)d_in[6];
    const float* b1 = (const float*)d_in[7];
    const float* w2 = (const float*)d_in[8];
    const float* b2 = (const float*)d_in[9];
    float* out = (float*)d_out;

    const int N = in_sizes[0] / 256;  // 50000
    const int E = in_sizes[1] / 2;    // 800000

    size_t o = 0;
    char* wsb = (char*)d_ws;
    auto alloc = [&](size_t nbytes) -> void* {
        void* p = wsb + o;
        o += (nbytes + 255) & ~(size_t)255;
        return p;
    };
    float* asrc = (float*)alloc((size_t)N * 4 * 4);
    float* adst = (float*)alloc((size_t)N * 4 * 4);
    int* cnt = (int*)alloc((size_t)N * 4);
    int* esrc = (int*)alloc((size_t)N * CAP * 4);
    ushort* xb = (ushort*)alloc((size_t)N * 256 * 2);
    ushort* G = (ushort*)alloc((size_t)N * 1024 * 2);
    ushort* WT2 = (ushort*)alloc((size_t)128 * 1024 * 2);
    ushort* w1t = (ushort*)alloc((size_t)128 * 128 * 2);
    float* watt = (float*)alloc((size_t)8 * 256 * 4);

    const int CB = (N + 3) / 4;              // cast blocks
    const int FB = (E + N + 255) / 256;      // fill blocks

    prep_small<<<780, 256, 0, stream>>>(W, att_src, att_dst, w1, cnt, watt,
                                        WT2, w1t, N);
    cast_fill<<<CB + FB, 256, 0, stream>>>(x, watt, xb, asrc, adst, ei, cnt,
                                           esrc, N, E, CB);
    aggregate_x<<<(N + 3) / 4, 256, 0, stream>>>(xb, cnt, esrc, asrc, adst, G,
                                                 N);
    tail_kernel<<<(N + 127) / 128, 256, 0, stream>>>(
        G, WT2, w1t, gat_bias, b1, w2, b2, out, N);
}

// Round 10
// 198.054 us; speedup vs baseline: 1.0638x; 1.0638x over previous
//
#include <hip/hip_runtime.h>
#include <hip/hip_bf16.h>

// ---------------------------------------------------------------------------
// Fused GAT (PyG GATConv, concat=False/head-mean) + 2-layer MLP head.
// 5 launches:
//   prep_small:  zero cnt + watt[8][256] + Wstk bf16 + w1t bf16
//   fill_lite:   direct-slot bucket fill (CAP=64 slots/node, slot-assign ONLY)
//   cast_score:  x_bf16 = bf16(x); asrc/adst = x @ watt (EXACT f32 scores)
//   aggregate_x: phase0: lane l = slot l computes w4 + den via shfl butterfly;
//                main loop: readlane-broadcast (w4, src) from lane i,
//                G[n,h*256+k] = 0.25/den_h * sum_e w4[h]*x_bf16[src,k]
//   tail_kernel: relu(G@Wstk+bias) -> relu(@w1t+b1) -> @w2+b2 -> out
// NOTE (round 9 lesson): merging fill into cast_score regressed 30+ us --
// the latency-bound atomic/scatter blocks and streaming cast blocks interfere
// when co-resident. Keep them as separate dispatches.
// CAP=64 == wavefront size: slot<->lane bijection. Max in-degree of
// Binomial(800k,1/50k)+self-loop ~40; P(any node > 64) ~ 1e-19.
// edge_index arrives as int32 [2,E].
// ---------------------------------------------------------------------------

#define LEAKY(x) ((x) > 0.0f ? (x) : 0.2f * (x))
#define CAP 64

typedef __attribute__((ext_vector_type(8))) short short8v;
typedef __attribute__((ext_vector_type(4))) float floatx4;

__device__ __forceinline__ unsigned f2b(float f) {  // f32 -> bf16 bits (RNE)
    unsigned u = __float_as_uint(f);
    return (u + 0x7fffu + ((u >> 16) & 1u)) >> 16;
}

__device__ __forceinline__ float rlf(float v, int i) {  // readlane (uniform i)
    return __uint_as_float(
        __builtin_amdgcn_readlane(__float_as_uint(v), (unsigned)i));
}

__device__ __forceinline__ void load_lds16(const void* g, void* lds) {
    __builtin_amdgcn_global_load_lds(
        (const __attribute__((address_space(1))) void*)g,
        (__attribute__((address_space(3))) void*)lds, 16, 0, 0);
}

// ---------------- prep: zero cnt | watt | Wstk bf16 | w1t bf16 --------------
// blocks [0,196): zero cnt; [196,204): watt; [204,716): WT2; [716,780): w1t
__global__ __launch_bounds__(256) void prep_small(
    const float* __restrict__ W, const float* __restrict__ att_src,
    const float* __restrict__ att_dst, const float* __restrict__ w1,
    int* __restrict__ cnt, float* __restrict__ watt,
    ushort* __restrict__ WT2, ushort* __restrict__ w1t, int N) {
    int pb = blockIdx.x;
    int t = threadIdx.x;
    if (pb < 196) {
        int i = pb * 256 + t;
        if (i < N) cnt[i] = 0;
    } else if (pb < 204) {
        int idx = (pb - 196) * 256 + t;  // 0..2047
        int k = idx >> 3;
        int h8 = idx & 7;
        int h = h8 & 3;
        const float* att = (h8 < 4) ? att_src : att_dst;
        const float* wrow = W + (size_t)k * 512 + h * 128;
        const float* arow = att + h * 128;
        float s = 0.f;
#pragma unroll 4
        for (int c = 0; c < 128; ++c) s += wrow[c] * arow[c];
        watt[h8 * 256 + k] = s;
    } else if (pb < 716) {
        int idx = (pb - 204) * 256 + t;  // 0..131071
        int c = idx >> 10;
        int kk = idx & 1023;
        int h = kk >> 8, k = kk & 255;
        WT2[c * 1024 + kk] = (ushort)f2b(W[(size_t)k * 512 + h * 128 + c]);
    } else {
        int idx = (pb - 716) * 256 + t;  // 0..16383
        int c = idx >> 7, k = idx & 127;
        w1t[c * 128 + k] = (ushort)f2b(w1[(size_t)k * 128 + c]);
    }
}

// ---------------- direct-slot bucket fill (slot assignment only) ------------
__global__ void fill_lite(const int* __restrict__ ei, int E, int N,
                          int* __restrict__ cnt, int* __restrict__ esrc) {
    int e = blockIdx.x * 256 + threadIdx.x;
    if (e >= E + N) return;
    int s, d;
    if (e < E) {
        s = ei[e];
        d = ei[E + e];
    } else {
        s = d = e - E;
    }
    if (d < 0 || d >= N || s < 0 || s >= N) return;
    int slot = atomicAdd(&cnt[d], 1);
    if (slot < CAP) esrc[d * CAP + slot] = s;
}

// ---------------- cast x -> bf16 + EXACT f32 attention scores ---------------
__global__ __launch_bounds__(256) void cast_score(
    const float* __restrict__ x, const float* __restrict__ watt,  // [8][256]
    ushort* __restrict__ xb, float* __restrict__ asrc,
    float* __restrict__ adst, int N) {
    int w = threadIdx.x >> 6, l = threadIdx.x & 63;
    int n = blockIdx.x * 4 + w;
    if (n >= N) return;
    float4 xv = *(const float4*)(x + (size_t)n * 256 + l * 4);
    ushort4 ub;
    ub.x = (ushort)f2b(xv.x);
    ub.y = (ushort)f2b(xv.y);
    ub.z = (ushort)f2b(xv.z);
    ub.w = (ushort)f2b(xv.w);
    *(ushort4*)(xb + (size_t)n * 256 + l * 4) = ub;

    float acc[8];
#pragma unroll
    for (int h8 = 0; h8 < 8; ++h8) {
        float4 wv = *(const float4*)(watt + h8 * 256 + l * 4);
        acc[h8] = xv.x * wv.x + xv.y * wv.y + xv.z * wv.z + xv.w * wv.w;
    }
#pragma unroll
    for (int o = 32; o; o >>= 1)
#pragma unroll
        for (int h8 = 0; h8 < 8; ++h8) acc[h8] += __shfl_xor(acc[h8], o);
    if (l == 0) {
#pragma unroll
        for (int h = 0; h < 4; ++h) {
            asrc[n * 4 + h] = acc[h];
            adst[n * 4 + h] = acc[4 + h];
        }
    }
}

// ---------------- aggregation in INPUT space --------------------------------
// one wave per node. Phase 0: lane l = slot l computes w4 (exp once per edge)
// + den via shfl butterfly. Main loop: edge i's w4/src broadcast via readlane
// (uniform index -> SGPR operand), gather 8B/lane of x_bf16[src].
#define EDGE_FMA_S(wx, wy, wz, ww, g)                                        \
    {                                                                        \
        float _e0 = __uint_as_float((g).x << 16);                            \
        float _e1 = __uint_as_float((g).x & 0xffff0000u);                    \
        float _e2 = __uint_as_float((g).y << 16);                            \
        float _e3 = __uint_as_float((g).y & 0xffff0000u);                    \
        acc[0][0] += (wx) * _e0; acc[0][1] += (wx) * _e1;                    \
        acc[0][2] += (wx) * _e2; acc[0][3] += (wx) * _e3;                    \
        acc[1][0] += (wy) * _e0; acc[1][1] += (wy) * _e1;                    \
        acc[1][2] += (wy) * _e2; acc[1][3] += (wy) * _e3;                    \
        acc[2][0] += (wz) * _e0; acc[2][1] += (wz) * _e1;                    \
        acc[2][2] += (wz) * _e2; acc[2][3] += (wz) * _e3;                    \
        acc[3][0] += (ww) * _e0; acc[3][1] += (ww) * _e1;                    \
        acc[3][2] += (ww) * _e2; acc[3][3] += (ww) * _e3;                    \
    }

__global__ __launch_bounds__(256) void aggregate_x(
    const ushort* __restrict__ xb, const int* __restrict__ cnt,
    const int* __restrict__ esrc, const float* __restrict__ asrc,
    const float* __restrict__ adst, ushort* __restrict__ G, int N) {
    const int t = threadIdx.x;
    const int wv = t >> 6, l = t & 63;
    const int n = blockIdx.x * 4 + wv;
    if (n >= N) return;
    const int beg = n * CAP;
    const int deg = min(cnt[n], CAP);
    const uint loff = (uint)l * 4u;

    // ---- phase 0: per-slot weights (lane l = slot l) + denominator ----
    float4 ad = ((const float4*)adst)[n];
    int s_l = 0;
    float4 wl = {0.f, 0.f, 0.f, 0.f};
    if (l < deg) {
        s_l = esrc[beg + l];
        float4 as = ((const float4*)asrc)[s_l];
        wl.x = __expf(LEAKY(as.x + ad.x));
        wl.y = __expf(LEAKY(as.y + ad.y));
        wl.z = __expf(LEAKY(as.z + ad.z));
        wl.w = __expf(LEAKY(as.w + ad.w));
    }
    float dx = wl.x, dy = wl.y, dz = wl.z, dw = wl.w;
#pragma unroll
    for (int o = 32; o; o >>= 1) {
        dx += __shfl_xor(dx, o);
        dy += __shfl_xor(dy, o);
        dz += __shfl_xor(dz, o);
        dw += __shfl_xor(dw, o);
    }
    const float sc0 = 0.25f / dx, sc1 = 0.25f / dy;
    const float sc2 = 0.25f / dz, sc3 = 0.25f / dw;

    float acc[4][4];
#pragma unroll
    for (int h = 0; h < 4; ++h)
#pragma unroll
        for (int j = 0; j < 4; ++j) acc[h][j] = 0.f;

    // ---- main loop: readlane broadcast of (src, w4), coalesced 8B gather ---
    int i = 0;
    const int deg4 = deg & ~3;
    for (; i < deg4; i += 4) {
        int s0 = __builtin_amdgcn_readlane(s_l, i + 0);
        int s1 = __builtin_amdgcn_readlane(s_l, i + 1);
        int s2 = __builtin_amdgcn_readlane(s_l, i + 2);
        int s3 = __builtin_amdgcn_readlane(s_l, i + 3);
        uint2 g0 = *(const uint2*)(xb + ((uint)s0 * 256u + loff));
        uint2 g1 = *(const uint2*)(xb + ((uint)s1 * 256u + loff));
        uint2 g2 = *(const uint2*)(xb + ((uint)s2 * 256u + loff));
        uint2 g3 = *(const uint2*)(xb + ((uint)s3 * 256u + loff));
        float w00 = rlf(wl.x, i + 0), w01 = rlf(wl.y, i + 0);
        float w02 = rlf(wl.z, i + 0), w03 = rlf(wl.w, i + 0);
        float w10 = rlf(wl.x, i + 1), w11 = rlf(wl.y, i + 1);
        float w12 = rlf(wl.z, i + 1), w13 = rlf(wl.w, i + 1);
        float w20 = rlf(wl.x, i + 2), w21 = rlf(wl.y, i + 2);
        float w22 = rlf(wl.z, i + 2), w23 = rlf(wl.w, i + 2);
        float w30 = rlf(wl.x, i + 3), w31 = rlf(wl.y, i + 3);
        float w32 = rlf(wl.z, i + 3), w33 = rlf(wl.w, i + 3);
        EDGE_FMA_S(w00, w01, w02, w03, g0);
        EDGE_FMA_S(w10, w11, w12, w13, g1);
        EDGE_FMA_S(w20, w21, w22, w23, g2);
        EDGE_FMA_S(w30, w31, w32, w33, g3);
    }
    for (; i < deg; ++i) {
        int s0 = __builtin_amdgcn_readlane(s_l, i);
        uint2 g0 = *(const uint2*)(xb + ((uint)s0 * 256u + loff));
        float w00 = rlf(wl.x, i), w01 = rlf(wl.y, i);
        float w02 = rlf(wl.z, i), w03 = rlf(wl.w, i);
        EDGE_FMA_S(w00, w01, w02, w03, g0);
    }

    const float sc[4] = {sc0, sc1, sc2, sc3};
#pragma unroll
    for (int h = 0; h < 4; ++h) {
        ushort4 o;
        o.x = (ushort)f2b(acc[h][0] * sc[h]);
        o.y = (ushort)f2b(acc[h][1] * sc[h]);
        o.z = (ushort)f2b(acc[h][2] * sc[h]);
        o.w = (ushort)f2b(acc[h][3] * sc[h]);
        *(ushort4*)(G + (size_t)n * 1024 + h * 256 + l * 4) = o;
    }
}

// ---------------- fused tail: G@Wstk -> relu -> @w1t -> relu -> @w2 ---------
__global__ __launch_bounds__(256) void tail_kernel(
    const ushort* __restrict__ Gb,      // [N,1024] bf16
    const ushort* __restrict__ Wstk,    // [128,1024] bf16 (row = out col)
    const ushort* __restrict__ w1t,     // [128,128] bf16 (row = out col)
    const float* __restrict__ gat_bias, const float* __restrict__ b1,
    const float* __restrict__ w2, const float* __restrict__ b2,
    float* __restrict__ out, int N) {
    __shared__ char smem[65 * 1024];
    char* AlsB = smem;                 // 16K stage-1 A tile
    char* BlsB = smem + 16 * 1024;     // 16K stage-1 B tile
    char* ndh = smem;                  // 32K nodeh bf16 (aliases A+B)
    char* w1ls = smem + 32 * 1024;     // 32K w1t bf16
    float* sums = (float*)(smem + 64 * 1024);  // [2][128] f32

    const int t = threadIdx.x;
    const int w = t >> 6;
    const int l = t & 63;
    const int wr = w >> 1, wc = w & 1;
    const int row0 = blockIdx.x * 128;

    float gbr[4], b1r[4], w2r[4];
#pragma unroll
    for (int n = 0; n < 4; ++n) {
        int cg = wc * 64 + n * 16 + (l & 15);
        gbr[n] = gat_bias[cg];
        b1r[n] = b1[cg];
        w2r[n] = w2[cg];
    }

    floatx4 acc[4][4];
#pragma unroll
    for (int m = 0; m < 4; ++m)
#pragma unroll
        for (int n = 0; n < 4; ++n) acc[m][n] = {0.f, 0.f, 0.f, 0.f};

    const int lr = l >> 3;
    const int kbyt = ((l & 7) ^ lr) << 4;
    const char* Abase = (const char*)Gb;
    const char* Bbase = (const char*)Wstk;

    // ---- stage 1: G @ Wstk, K=1024 ----
    for (int ks = 0; ks < 16; ++ks) {
        const int k0b = ks * 128;
#pragma unroll
        for (int c = 0; c < 4; ++c) {
            int rowt = w * 32 + c * 8 + lr;
            int rA = row0 + rowt;
            if (rA >= N) rA = N - 1;
            load_lds16(Abase + (size_t)rA * 2048 + k0b + kbyt,
                       AlsB + (w * 4 + c) * 1024);
            load_lds16(Bbase + (size_t)rowt * 2048 + k0b + kbyt,
                       BlsB + (w * 4 + c) * 1024);
        }
        __syncthreads();

#pragma unroll
        for (int kk = 0; kk < 2; ++kk) {
            const int kb_g = kk * 64 + (l >> 4) * 16;
            const int swz = (l & 7) << 4;
            short8v a[4], b[4];
#pragma unroll
            for (int m = 0; m < 4; ++m) {
                int row = wr * 64 + m * 16 + (l & 15);
                a[m] = *(const short8v*)(AlsB + row * 128 + (kb_g ^ swz));
            }
#pragma unroll
            for (int n = 0; n < 4; ++n) {
                int row = wc * 64 + n * 16 + (l & 15);
                b[n] = *(const short8v*)(BlsB + row * 128 + (kb_g ^ swz));
            }
#pragma unroll
            for (int m = 0; m < 4; ++m)
#pragma unroll
                for (int n = 0; n < 4; ++n)
                    acc[m][n] = __builtin_amdgcn_mfma_f32_16x16x32_bf16(
                        a[m], b[n], acc[m][n], 0, 0, 0);
        }
        __syncthreads();
    }

    // ---- epilogue 1: stage w1t (async) + write nodeh bf16 to LDS ----
#pragma unroll
    for (int p = 0; p < 8; ++p) {
        int row = p * 16 + w * 4 + (l >> 4);
        int bcol = (l & 15) * 16;
        load_lds16((const char*)w1t + row * 256 + (bcol ^ ((row & 7) << 4)),
                   w1ls + p * 4096 + w * 1024);
    }
#pragma unroll
    for (int m = 0; m < 4; ++m) {
#pragma unroll
        for (int reg = 0; reg < 4; ++reg) {
            int r = wr * 64 + m * 16 + ((l >> 4) << 2) + reg;
            int srow = (r & 7) << 4;
#pragma unroll
            for (int n = 0; n < 4; ++n) {
                int c = wc * 64 + n * 16 + (l & 15);
                float v = acc[m][n][reg] + gbr[n];
                v = v > 0.f ? v : 0.f;
                *(ushort*)(ndh + r * 256 + ((2 * c) ^ srow)) = (ushort)f2b(v);
            }
        }
    }
    __syncthreads();  // drains vmcnt (w1ls) + lgkm (ndh writes)

    // ---- stage 2: y1 = relu(nodeh @ w1t + b1), K=128 ----
    floatx4 acc2[4][4];
#pragma unroll
    for (int m = 0; m < 4; ++m)
#pragma unroll
        for (int n = 0; n < 4; ++n) acc2[m][n] = {0.f, 0.f, 0.f, 0.f};

#pragma unroll
    for (int kk = 0; kk < 4; ++kk) {
        const int kb = kk * 64 + (l >> 4) * 16;
        short8v a2[4], b2f[4];
#pragma unroll
        for (int m = 0; m < 4; ++m) {
            int r = wr * 64 + m * 16 + (l & 15);
            a2[m] = *(const short8v*)(ndh + r * 256 + (kb ^ ((r & 7) << 4)));
        }
#pragma unroll
        for (int n = 0; n < 4; ++n) {
            int r = wc * 64 + n * 16 + (l & 15);
            b2f[n] = *(const short8v*)(w1ls + r * 256 + (kb ^ ((r & 7) << 4)));
        }
#pragma unroll
        for (int m = 0; m < 4; ++m)
#pragma unroll
            for (int n = 0; n < 4; ++n)
                acc2[m][n] = __builtin_amdgcn_mfma_f32_16x16x32_bf16(
                    a2[m], b2f[n], acc2[m][n], 0, 0, 0);
    }

    // ---- stage 3: out = y1 @ w2 + b2 (in-register) ----
    float part[4][4];
#pragma unroll
    for (int m = 0; m < 4; ++m)
#pragma unroll
        for (int reg = 0; reg < 4; ++reg) {
            float s = 0.f;
#pragma unroll
            for (int n = 0; n < 4; ++n) {
                float y = acc2[m][n][reg] + b1r[n];
                y = y > 0.f ? y : 0.f;
                s += y * w2r[n];
            }
            part[m][reg] = s;
        }
#pragma unroll
    for (int o = 1; o < 16; o <<= 1)
#pragma unroll
        for (int m = 0; m < 4; ++m)
#pragma unroll
            for (int reg = 0; reg < 4; ++reg)
                part[m][reg] += __shfl_xor(part[m][reg], o);
    if ((l & 15) == 0) {
#pragma unroll
        for (int m = 0; m < 4; ++m)
#pragma unroll
            for (int reg = 0; reg < 4; ++reg) {
                int r = wr * 64 + m * 16 + ((l >> 4) << 2) + reg;
                sums[wc * 128 + r] = part[m][reg];
            }
    }
    __syncthreads();
    if (t < 128) {
        int rg = row0 + t;
        if (rg < N) out[rg] = sums[t] + sums[128 + t] + b2[0];
    }
}

// ---------------------------------------------------------------------------
extern "C" void kernel_launch(void* const* d_in, const int* in_sizes, int n_in,
                              void* d_out, int out_size, void* d_ws,
                              size_t ws_size, hipStream_t stream) {
    const float* x = (const float*)d_in[0];
    const int* ei = (const int*)d_in[1];  // int32 [2,E]
    const float* W = (const float*)d_in[2];
    const float* att_src = (const float*)d_in[3];
    const float* att_dst = (const float*)d_in[4];
    const float* gat_bias = (const float*)d_in[5];
    const float* w1 = (const float*)d_in[6];
    const float* b1 = (const float*)d_in[7];
    const float* w2 = (const float*)d_in[8];
    const float* b2 = (const float*)d_in[9];
    float* out = (float*)d_out;

    const int N = in_sizes[0] / 256;  // 50000
    const int E = in_sizes[1] / 2;    // 800000

    size_t o = 0;
    char* wsb = (char*)d_ws;
    auto alloc = [&](size_t nbytes) -> void* {
        void* p = wsb + o;
        o += (nbytes + 255) & ~(size_t)255;
        return p;
    };
    float* asrc = (float*)alloc((size_t)N * 4 * 4);
    float* adst = (float*)alloc((size_t)N * 4 * 4);
    int* cnt = (int*)alloc((size_t)N * 4);
    int* esrc = (int*)alloc((size_t)N * CAP * 4);
    ushort* xb = (ushort*)alloc((size_t)N * 256 * 2);
    ushort* G = (ushort*)alloc((size_t)N * 1024 * 2);
    ushort* WT2 = (ushort*)alloc((size_t)128 * 1024 * 2);
    ushort* w1t = (ushort*)alloc((size_t)128 * 128 * 2);
    float* watt = (float*)alloc((size_t)8 * 256 * 4);

    prep_small<<<780, 256, 0, stream>>>(W, att_src, att_dst, w1, cnt, watt,
                                        WT2, w1t, N);
    fill_lite<<<(E + N + 255) / 256, 256, 0, stream>>>(ei, E, N, cnt, esrc);
    cast_score<<<(N + 3) / 4, 256, 0, stream>>>(x, watt, xb, asrc, adst, N);
    aggregate_x<<<(N + 3) / 4, 256, 0, stream>>>(xb, cnt, esrc, asrc, adst, G,
                                                 N);
    tail_kernel<<<(N + 127) / 128, 256, 0, stream>>>(
        G, WT2, w1t, gat_bias, b1, w2, b2, out, N);
}

// Round 11
// 196.917 us; speedup vs baseline: 1.0700x; 1.0058x over previous
//
#include <hip/hip_runtime.h>
#include <hip/hip_bf16.h>

// ---------------------------------------------------------------------------
// Fused GAT (PyG GATConv, concat=False/head-mean) + 2-layer MLP head.
// 5 launches:
//   prep_small:  zero cnt + watt[8][256] + Wstk bf16 + w1t bf16
//   fill_lite:   direct-slot bucket fill (CAP=64 slots/node, slot-assign ONLY)
//   cast_score:  x_bf16 = bf16(x); asrc/adst = x @ watt (EXACT f32 scores)
//   aggregate_x: phase0: lane l = slot l computes w4 + den via shfl butterfly;
//                main loop: readlane-broadcast (w4, src) from lane i,
//                packed f32x2 FMA (v_pk_fma_f32) -- 8 pk-FMA/edge/lane
//   tail_kernel: relu(G@Wstk+bias) -> relu(@w1t+b1) -> @w2+b2 -> out
// Round-9 lesson kept: fill and cast stay SEPARATE dispatches (merging the
// latency-bound atomic/scatter blocks with streaming cast blocks regressed).
// CAP=64 == wavefront size: slot<->lane bijection. P(any deg > 64) ~ 1e-19.
// edge_index arrives as int32 [2,E].
// ---------------------------------------------------------------------------

#define LEAKY(x) ((x) > 0.0f ? (x) : 0.2f * (x))
#define CAP 64

typedef __attribute__((ext_vector_type(8))) short short8v;
typedef __attribute__((ext_vector_type(4))) float floatx4;
typedef __attribute__((ext_vector_type(2))) float f32x2;

__device__ __forceinline__ unsigned f2b(float f) {  // f32 -> bf16 bits (RNE)
    unsigned u = __float_as_uint(f);
    return (u + 0x7fffu + ((u >> 16) & 1u)) >> 16;
}

__device__ __forceinline__ float rlf(float v, int i) {  // readlane (uniform i)
    return __uint_as_float(
        __builtin_amdgcn_readlane(__float_as_uint(v), (unsigned)i));
}

__device__ __forceinline__ void load_lds16(const void* g, void* lds) {
    __builtin_amdgcn_global_load_lds(
        (const __attribute__((address_space(1))) void*)g,
        (__attribute__((address_space(3))) void*)lds, 16, 0, 0);
}

// ---------------- prep: zero cnt | watt | Wstk bf16 | w1t bf16 --------------
// blocks [0,196): zero cnt; [196,204): watt; [204,716): WT2; [716,780): w1t
// WT2/w1t mappings are READ-coalesced (scattered writes are absorbed by L2).
__global__ __launch_bounds__(256) void prep_small(
    const float* __restrict__ W, const float* __restrict__ att_src,
    const float* __restrict__ att_dst, const float* __restrict__ w1,
    int* __restrict__ cnt, float* __restrict__ watt,
    ushort* __restrict__ WT2, ushort* __restrict__ w1t, int N) {
    int pb = blockIdx.x;
    int t = threadIdx.x;
    if (pb < 196) {
        int i = pb * 256 + t;
        if (i < N) cnt[i] = 0;
    } else if (pb < 204) {
        int idx = (pb - 196) * 256 + t;  // 0..2047
        int k = idx >> 3;
        int h8 = idx & 7;
        int h = h8 & 3;
        const float* att = (h8 < 4) ? att_src : att_dst;
        const float* wrow = W + (size_t)k * 512 + h * 128;
        const float* arow = att + h * 128;
        float s = 0.f;
#pragma unroll 4
        for (int c = 0; c < 128; ++c) s += wrow[c] * arow[c];
        watt[h8 * 256 + k] = s;
    } else if (pb < 716) {
        int idx = (pb - 204) * 256 + t;  // 0..131071
        int c = idx & 127;               // fast: coalesced W read
        int h = (idx >> 7) & 3;
        int k = idx >> 9;
        WT2[c * 1024 + h * 256 + k] = (ushort)f2b(W[(size_t)k * 512 + h * 128 + c]);
    } else {
        int idx = (pb - 716) * 256 + t;  // 0..16383
        int c = idx & 127;               // fast: coalesced w1 read
        int k = idx >> 7;
        w1t[c * 128 + k] = (ushort)f2b(w1[(size_t)k * 128 + c]);
    }
}

// ---------------- direct-slot bucket fill (slot assignment only) ------------
__global__ void fill_lite(const int* __restrict__ ei, int E, int N,
                          int* __restrict__ cnt, int* __restrict__ esrc) {
    int e = blockIdx.x * 256 + threadIdx.x;
    if (e >= E + N) return;
    int s, d;
    if (e < E) {
        s = ei[e];
        d = ei[E + e];
    } else {
        s = d = e - E;
    }
    if (d < 0 || d >= N || s < 0 || s >= N) return;
    int slot = atomicAdd(&cnt[d], 1);
    if (slot < CAP) esrc[d * CAP + slot] = s;
}

// ---------------- cast x -> bf16 + EXACT f32 attention scores ---------------
__global__ __launch_bounds__(256) void cast_score(
    const float* __restrict__ x, const float* __restrict__ watt,  // [8][256]
    ushort* __restrict__ xb, float* __restrict__ asrc,
    float* __restrict__ adst, int N) {
    int w = threadIdx.x >> 6, l = threadIdx.x & 63;
    int n = blockIdx.x * 4 + w;
    if (n >= N) return;
    float4 xv = *(const float4*)(x + (size_t)n * 256 + l * 4);
    ushort4 ub;
    ub.x = (ushort)f2b(xv.x);
    ub.y = (ushort)f2b(xv.y);
    ub.z = (ushort)f2b(xv.z);
    ub.w = (ushort)f2b(xv.w);
    *(ushort4*)(xb + (size_t)n * 256 + l * 4) = ub;

    float acc[8];
#pragma unroll
    for (int h8 = 0; h8 < 8; ++h8) {
        float4 wv = *(const float4*)(watt + h8 * 256 + l * 4);
        acc[h8] = xv.x * wv.x + xv.y * wv.y + xv.z * wv.z + xv.w * wv.w;
    }
#pragma unroll
    for (int o = 32; o; o >>= 1)
#pragma unroll
        for (int h8 = 0; h8 < 8; ++h8) acc[h8] += __shfl_xor(acc[h8], o);
    if (l == 0) {
#pragma unroll
        for (int h = 0; h < 4; ++h) {
            asrc[n * 4 + h] = acc[h];
            adst[n * 4 + h] = acc[4 + h];
        }
    }
}

// ---------------- aggregation in INPUT space (packed f32x2 FMA) -------------
// one wave per node. Phase 0: lane l = slot l computes w4 + den via shfl
// butterfly. Main loop: edge i's (src, w4) broadcast via readlane; each lane
// gathers 8B (4 bf16 ch) and does 8 v_pk_fma_f32 (4 heads x 2 ch-pairs).
#define EDGE_PK(w0, w1, w2, w3, g)                                           \
    {                                                                        \
        f32x2 _e01 = {__uint_as_float((g).x << 16),                          \
                      __uint_as_float((g).x & 0xffff0000u)};                 \
        f32x2 _e23 = {__uint_as_float((g).y << 16),                          \
                      __uint_as_float((g).y & 0xffff0000u)};                 \
        f32x2 _w;                                                            \
        _w = (f32x2){(w0), (w0)};                                            \
        acc[0][0] += _w * _e01; acc[0][1] += _w * _e23;                      \
        _w = (f32x2){(w1), (w1)};                                            \
        acc[1][0] += _w * _e01; acc[1][1] += _w * _e23;                      \
        _w = (f32x2){(w2), (w2)};                                            \
        acc[2][0] += _w * _e01; acc[2][1] += _w * _e23;                      \
        _w = (f32x2){(w3), (w3)};                                            \
        acc[3][0] += _w * _e01; acc[3][1] += _w * _e23;                      \
    }

__global__ __launch_bounds__(256) void aggregate_x(
    const ushort* __restrict__ xb, const int* __restrict__ cnt,
    const int* __restrict__ esrc, const float* __restrict__ asrc,
    const float* __restrict__ adst, ushort* __restrict__ G, int N) {
    const int t = threadIdx.x;
    const int wv = t >> 6, l = t & 63;
    const int n = blockIdx.x * 4 + wv;
    if (n >= N) return;
    const int beg = n * CAP;
    const int deg = min(cnt[n], CAP);
    const uint loff = (uint)l * 4u;

    // ---- phase 0: per-slot weights (lane l = slot l) + denominator ----
    float4 ad = ((const float4*)adst)[n];
    int s_l = 0;
    float4 wl = {0.f, 0.f, 0.f, 0.f};
    if (l < deg) {
        s_l = esrc[beg + l];
        float4 as = ((const float4*)asrc)[s_l];
        wl.x = __expf(LEAKY(as.x + ad.x));
        wl.y = __expf(LEAKY(as.y + ad.y));
        wl.z = __expf(LEAKY(as.z + ad.z));
        wl.w = __expf(LEAKY(as.w + ad.w));
    }
    float dx = wl.x, dy = wl.y, dz = wl.z, dw = wl.w;
#pragma unroll
    for (int o = 32; o; o >>= 1) {
        dx += __shfl_xor(dx, o);
        dy += __shfl_xor(dy, o);
        dz += __shfl_xor(dz, o);
        dw += __shfl_xor(dw, o);
    }
    const float sc[4] = {0.25f / dx, 0.25f / dy, 0.25f / dz, 0.25f / dw};

    f32x2 acc[4][2];
#pragma unroll
    for (int h = 0; h < 4; ++h) {
        acc[h][0] = (f32x2){0.f, 0.f};
        acc[h][1] = (f32x2){0.f, 0.f};
    }

    // ---- main loop: readlane broadcast of (src, w4), coalesced 8B gather ---
    int i = 0;
    const int deg4 = deg & ~3;
    for (; i < deg4; i += 4) {
        int s0 = __builtin_amdgcn_readlane(s_l, i + 0);
        int s1 = __builtin_amdgcn_readlane(s_l, i + 1);
        int s2 = __builtin_amdgcn_readlane(s_l, i + 2);
        int s3 = __builtin_amdgcn_readlane(s_l, i + 3);
        uint2 g0 = *(const uint2*)(xb + ((uint)s0 * 256u + loff));
        uint2 g1 = *(const uint2*)(xb + ((uint)s1 * 256u + loff));
        uint2 g2 = *(const uint2*)(xb + ((uint)s2 * 256u + loff));
        uint2 g3 = *(const uint2*)(xb + ((uint)s3 * 256u + loff));
        float w00 = rlf(wl.x, i + 0), w01 = rlf(wl.y, i + 0);
        float w02 = rlf(wl.z, i + 0), w03 = rlf(wl.w, i + 0);
        float w10 = rlf(wl.x, i + 1), w11 = rlf(wl.y, i + 1);
        float w12 = rlf(wl.z, i + 1), w13 = rlf(wl.w, i + 1);
        float w20 = rlf(wl.x, i + 2), w21 = rlf(wl.y, i + 2);
        float w22 = rlf(wl.z, i + 2), w23 = rlf(wl.w, i + 2);
        float w30 = rlf(wl.x, i + 3), w31 = rlf(wl.y, i + 3);
        float w32 = rlf(wl.z, i + 3), w33 = rlf(wl.w, i + 3);
        EDGE_PK(w00, w01, w02, w03, g0);
        EDGE_PK(w10, w11, w12, w13, g1);
        EDGE_PK(w20, w21, w22, w23, g2);
        EDGE_PK(w30, w31, w32, w33, g3);
    }
    for (; i < deg; ++i) {
        int s0 = __builtin_amdgcn_readlane(s_l, i);
        uint2 g0 = *(const uint2*)(xb + ((uint)s0 * 256u + loff));
        float w00 = rlf(wl.x, i), w01 = rlf(wl.y, i);
        float w02 = rlf(wl.z, i), w03 = rlf(wl.w, i);
        EDGE_PK(w00, w01, w02, w03, g0);
    }

#pragma unroll
    for (int h = 0; h < 4; ++h) {
        ushort4 o;
        o.x = (ushort)f2b(acc[h][0][0] * sc[h]);
        o.y = (ushort)f2b(acc[h][0][1] * sc[h]);
        o.z = (ushort)f2b(acc[h][1][0] * sc[h]);
        o.w = (ushort)f2b(acc[h][1][1] * sc[h]);
        *(ushort4*)(G + (size_t)n * 1024 + h * 256 + l * 4) = o;
    }
}

// ---------------- fused tail: G@Wstk -> relu -> @w1t -> relu -> @w2 ---------
__global__ __launch_bounds__(256) void tail_kernel(
    const ushort* __restrict__ Gb,      // [N,1024] bf16
    const ushort* __restrict__ Wstk,    // [128,1024] bf16 (row = out col)
    const ushort* __restrict__ w1t,     // [128,128] bf16 (row = out col)
    const float* __restrict__ gat_bias, const float* __restrict__ b1,
    const float* __restrict__ w2, const float* __restrict__ b2,
    float* __restrict__ out, int N) {
    __shared__ char smem[65 * 1024];
    char* AlsB = smem;                 // 16K stage-1 A tile
    char* BlsB = smem + 16 * 1024;     // 16K stage-1 B tile
    char* ndh = smem;                  // 32K nodeh bf16 (aliases A+B)
    char* w1ls = smem + 32 * 1024;     // 32K w1t bf16
    float* sums = (float*)(smem + 64 * 1024);  // [2][128] f32

    const int t = threadIdx.x;
    const int w = t >> 6;
    const int l = t & 63;
    const int wr = w >> 1, wc = w & 1;
    const int row0 = blockIdx.x * 128;

    float gbr[4], b1r[4], w2r[4];
#pragma unroll
    for (int n = 0; n < 4; ++n) {
        int cg = wc * 64 + n * 16 + (l & 15);
        gbr[n] = gat_bias[cg];
        b1r[n] = b1[cg];
        w2r[n] = w2[cg];
    }

    floatx4 acc[4][4];
#pragma unroll
    for (int m = 0; m < 4; ++m)
#pragma unroll
        for (int n = 0; n < 4; ++n) acc[m][n] = {0.f, 0.f, 0.f, 0.f};

    const int lr = l >> 3;
    const int kbyt = ((l & 7) ^ lr) << 4;
    const char* Abase = (const char*)Gb;
    const char* Bbase = (const char*)Wstk;

    // ---- stage 1: G @ Wstk, K=1024 ----
    for (int ks = 0; ks < 16; ++ks) {
        const int k0b = ks * 128;
#pragma unroll
        for (int c = 0; c < 4; ++c) {
            int rowt = w * 32 + c * 8 + lr;
            int rA = row0 + rowt;
            if (rA >= N) rA = N - 1;
            load_lds16(Abase + (size_t)rA * 2048 + k0b + kbyt,
                       AlsB + (w * 4 + c) * 1024);
            load_lds16(Bbase + (size_t)rowt * 2048 + k0b + kbyt,
                       BlsB + (w * 4 + c) * 1024);
        }
        __syncthreads();

#pragma unroll
        for (int kk = 0; kk < 2; ++kk) {
            const int kb_g = kk * 64 + (l >> 4) * 16;
            const int swz = (l & 7) << 4;
            short8v a[4], b[4];
#pragma unroll
            for (int m = 0; m < 4; ++m) {
                int row = wr * 64 + m * 16 + (l & 15);
                a[m] = *(const short8v*)(AlsB + row * 128 + (kb_g ^ swz));
            }
#pragma unroll
            for (int n = 0; n < 4; ++n) {
                int row = wc * 64 + n * 16 + (l & 15);
                b[n] = *(const short8v*)(BlsB + row * 128 + (kb_g ^ swz));
            }
#pragma unroll
            for (int m = 0; m < 4; ++m)
#pragma unroll
                for (int n = 0; n < 4; ++n)
                    acc[m][n] = __builtin_amdgcn_mfma_f32_16x16x32_bf16(
                        a[m], b[n], acc[m][n], 0, 0, 0);
        }
        __syncthreads();
    }

    // ---- epilogue 1: stage w1t (async) + write nodeh bf16 to LDS ----
#pragma unroll
    for (int p = 0; p < 8; ++p) {
        int row = p * 16 + w * 4 + (l >> 4);
        int bcol = (l & 15) * 16;
        load_lds16((const char*)w1t + row * 256 + (bcol ^ ((row & 7) << 4)),
                   w1ls + p * 4096 + w * 1024);
    }
#pragma unroll
    for (int m = 0; m < 4; ++m) {
#pragma unroll
        for (int reg = 0; reg < 4; ++reg) {
            int r = wr * 64 + m * 16 + ((l >> 4) << 2) + reg;
            int srow = (r & 7) << 4;
#pragma unroll
            for (int n = 0; n < 4; ++n) {
                int c = wc * 64 + n * 16 + (l & 15);
                float v = acc[m][n][reg] + gbr[n];
                v = v > 0.f ? v : 0.f;
                *(ushort*)(ndh + r * 256 + ((2 * c) ^ srow)) = (ushort)f2b(v);
            }
        }
    }
    __syncthreads();  // drains vmcnt (w1ls) + lgkm (ndh writes)

    // ---- stage 2: y1 = relu(nodeh @ w1t + b1), K=128 ----
    floatx4 acc2[4][4];
#pragma unroll
    for (int m = 0; m < 4; ++m)
#pragma unroll
        for (int n = 0; n < 4; ++n) acc2[m][n] = {0.f, 0.f, 0.f, 0.f};

#pragma unroll
    for (int kk = 0; kk < 4; ++kk) {
        const int kb = kk * 64 + (l >> 4) * 16;
        short8v a2[4], b2f[4];
#pragma unroll
        for (int m = 0; m < 4; ++m) {
            int r = wr * 64 + m * 16 + (l & 15);
            a2[m] = *(const short8v*)(ndh + r * 256 + (kb ^ ((r & 7) << 4)));
        }
#pragma unroll
        for (int n = 0; n < 4; ++n) {
            int r = wc * 64 + n * 16 + (l & 15);
            b2f[n] = *(const short8v*)(w1ls + r * 256 + (kb ^ ((r & 7) << 4)));
        }
#pragma unroll
        for (int m = 0; m < 4; ++m)
#pragma unroll
            for (int n = 0; n < 4; ++n)
                acc2[m][n] = __builtin_amdgcn_mfma_f32_16x16x32_bf16(
                    a2[m], b2f[n], acc2[m][n], 0, 0, 0);
    }

    // ---- stage 3: out = y1 @ w2 + b2 (in-register) ----
    float part[4][4];
#pragma unroll
    for (int m = 0; m < 4; ++m)
#pragma unroll
        for (int reg = 0; reg < 4; ++reg) {
            float s = 0.f;
#pragma unroll
            for (int n = 0; n < 4; ++n) {
                float y = acc2[m][n][reg] + b1r[n];
                y = y > 0.f ? y : 0.f;
                s += y * w2r[n];
            }
            part[m][reg] = s;
        }
#pragma unroll
    for (int o = 1; o < 16; o <<= 1)
#pragma unroll
        for (int m = 0; m < 4; ++m)
#pragma unroll
            for (int reg = 0; reg < 4; ++reg)
                part[m][reg] += __shfl_xor(part[m][reg], o);
    if ((l & 15) == 0) {
#pragma unroll
        for (int m = 0; m < 4; ++m)
#pragma unroll
            for (int reg = 0; reg < 4; ++reg) {
                int r = wr * 64 + m * 16 + ((l >> 4) << 2) + reg;
                sums[wc * 128 + r] = part[m][reg];
            }
    }
    __syncthreads();
    if (t < 128) {
        int rg = row0 + t;
        if (rg < N) out[rg] = sums[t] + sums[128 + t] + b2[0];
    }
}

// ---------------------------------------------------------------------------
extern "C" void kernel_launch(void* const* d_in, const int* in_sizes, int n_in,
                              void* d_out, int out_size, void* d_ws,
                              size_t ws_size, hipStream_t stream) {
    const float* x = (const float*)d_in[0];
    const int* ei = (const int*)d_in[1];  // int32 [2,E]
    const float* W = (const float*)d_in[2];
    const float* att_src = (const float*)d_in[3];
    const float* att_dst = (const float*)d_in[4];
    const float* gat_bias = (const float*)d_in[5];
    const float* w1 = (const float*)d_in[6];
    const float* b1 = (const float*)d_in[7];
    const float* w2 = (const float*)d_in[8];
    const float* b2 = (const float*)d_in[9];
    float* out = (float*)d_out;

    const int N = in_sizes[0] / 256;  // 50000
    const int E = in_sizes[1] / 2;    // 800000

    size_t o = 0;
    char* wsb = (char*)d_ws;
    auto alloc = [&](size_t nbytes) -> void* {
        void* p = wsb + o;
        o += (nbytes + 255) & ~(size_t)255;
        return p;
    };
    float* asrc = (float*)alloc((size_t)N * 4 * 4);
    float* adst = (float*)alloc((size_t)N * 4 * 4);
    int* cnt = (int*)alloc((size_t)N * 4);
    int* esrc = (int*)alloc((size_t)N * CAP * 4);
    ushort* xb = (ushort*)alloc((size_t)N * 256 * 2);
    ushort* G = (ushort*)alloc((size_t)N * 1024 * 2);
    ushort* WT2 = (ushort*)alloc((size_t)128 * 1024 * 2);
    ushort* w1t = (ushort*)alloc((size_t)128 * 128 * 2);
    float* watt = (float*)alloc((size_t)8 * 256 * 4);

    prep_small<<<780, 256, 0, stream>>>(W, att_src, att_dst, w1, cnt, watt,
                                        WT2, w1t, N);
    fill_lite<<<(E + N + 255) / 256, 256, 0, stream>>>(ei, E, N, cnt, esrc);
    cast_score<<<(N + 3) / 4, 256, 0, stream>>>(x, watt, xb, asrc, adst, N);
    aggregate_x<<<(N + 3) / 4, 256, 0, stream>>>(xb, cnt, esrc, asrc, adst, G,
                                                 N);
    tail_kernel<<<(N + 127) / 128, 256, 0, stream>>>(
        G, WT2, w1t, gat_bias, b1, w2, b2, out, N);
}